// Round 8
// baseline (2977.756 us; speedup 1.0000x reference)
//
#include <hip/hip_runtime.h>
#include <hip/hip_bf16.h>

#define B_  8
#define L_  512
#define DM  512
#define NL  4
#define DS  16
#define HOR 96
#define DC  4
#define DI  1024
#define DTR 32

#define CHUNK 16
#define NCHK (L_/CHUNK)   // 32
#define GRID 512          // 2 blocks/CU guaranteed co-resident (see launch_bounds)

typedef __bf16 bf16_t;
typedef __bf16 b8_t __attribute__((ext_vector_type(8)));
typedef float  f4_t __attribute__((ext_vector_type(4)));

__device__ __forceinline__ float sigmoidf_(float x){ return 1.f/(1.f+__expf(-x)); }

__device__ __forceinline__ void async16(const bf16_t* g, bf16_t* l){
  __builtin_amdgcn_global_load_lds((const __attribute__((address_space(1))) void*)g,
                                   (__attribute__((address_space(3))) void*)l, 16, 0, 0);
}

// ---------- two-level device-scope grid barrier (one-shot counters, memset per launch) ----------
__device__ __forceinline__ void gbar(int* bar, int id){
  __syncthreads();
  if (threadIdx.x == 0){
    int* base = bar + id*1024;
    int leaf = blockIdx.x & 31;                 // 16 blocks per leaf
    __threadfence();
    if (__hip_atomic_fetch_add(base + leaf*16, 1, __ATOMIC_ACQ_REL, __HIP_MEMORY_SCOPE_AGENT) == (GRID/32 - 1)){
      if (__hip_atomic_fetch_add(base + 512, 1, __ATOMIC_ACQ_REL, __HIP_MEMORY_SCOPE_AGENT) == 31){
        __hip_atomic_store(base + 520, 1, __ATOMIC_RELEASE, __HIP_MEMORY_SCOPE_AGENT);
      }
    }
    int sp = 0;
    while (__hip_atomic_load(base + 520, __ATOMIC_ACQUIRE, __HIP_MEMORY_SCOPE_AGENT) == 0){
      if (++sp > (1<<24)) break;                // safety valve vs infinite hang
      __builtin_amdgcn_s_sleep(2);
    }
    __threadfence();
  }
  __syncthreads();
}

// ---------- fused f32 -> bf16 weight convert ----------
__global__ __launch_bounds__(256) void k_cvtall(const float* __restrict__ p0, bf16_t* __restrict__ o0,
                                                const float* __restrict__ p1, bf16_t* __restrict__ o1,
                                                const float* __restrict__ p2, bf16_t* __restrict__ o2,
                                                const float* __restrict__ p3, bf16_t* __restrict__ o3){
  int j = blockIdx.x*256 + threadIdx.x;   // v4 index
  const int S0=1048576, S1=65536, S2=32768;
  const float* src; bf16_t* dst;
  if (j < S0){ src=p0; dst=o0; }
  else if ((j-=S0) < S1){ src=p1; dst=o1; }
  else if ((j-=S1) < S2){ src=p2; dst=o2; }
  else { j-=S2; src=p3; dst=o3; }
  f4_t v = ((const f4_t*)src)[j];
  bf16_t* o = dst + (size_t)j*4;
  o[0]=(bf16_t)v[0]; o[1]=(bf16_t)v[1]; o[2]=(bf16_t)v[2]; o[3]=(bf16_t)v[3];
}

// ---------- embed ----------
__global__ __launch_bounds__(256) void k_embed(const float* __restrict__ x, const float* __restrict__ ew,
                                               const float* __restrict__ eb, float* __restrict__ h){
  int idx = blockIdx.x*256 + threadIdx.x;   // B*L*DM
  int d = idx & (DM-1); int t = idx >> 9;
  h[idx] = x[t]*ew[d] + eb[d];
}

// ---------- persistent megakernel: 4 layers x 8 stages with grid barriers ----------
__global__ __launch_bounds__(256, 2) void k_mega(
    float* __restrict__ hbuf, const float* __restrict__ nw_all,
    const bf16_t* __restrict__ w_in_all, const bf16_t* __restrict__ w_xp_all,
    const bf16_t* __restrict__ w_dt_all, const bf16_t* __restrict__ w_out_all,
    const float* __restrict__ cw_all, const float* __restrict__ cb_all,
    const float* __restrict__ dtb_all, const float* __restrict__ alog_all,
    const float* __restrict__ Dp_all,
    bf16_t* __restrict__ hnorm, bf16_t* __restrict__ xzbf,
    bf16_t* __restrict__ xinbf, bf16_t* __restrict__ delta,
    bf16_t* __restrict__ ybf, float* __restrict__ dbc,
    float* __restrict__ dbcp, float* __restrict__ hend,
    float* __restrict__ aphin, int* __restrict__ bar){
  __shared__ long long smem_ll[12*1024/8 + 64];
  char* smem = (char*)smem_ll;
  int tid = threadIdx.x, bid = blockIdx.x;
  int wave = tid>>6, lane = tid&63;
  int barid = 0;

  for (int layer=0; layer<NL; layer++){
    const float*  nw  = nw_all   + layer*DM;
    const bf16_t* Wi  = w_in_all + (size_t)layer*2*DI*DM;
    const bf16_t* Wxp = w_xp_all + (size_t)layer*64*DI;
    const bf16_t* Wdt = w_dt_all + (size_t)layer*DI*DTR;
    const bf16_t* Wo  = w_out_all+ (size_t)layer*DM*DI;
    const float*  cw  = cw_all  + layer*DI*DC;
    const float*  cb  = cb_all  + layer*DI;
    const float*  dtb = dtb_all + layer*DI;
    const float*  alog= alog_all+ (size_t)layer*DI*DS;
    const float*  Dp  = Dp_all  + layer*DI;

    // ===== stage 1: rmsnorm (wave per token) =====
    for (int t = bid*4 + wave; t < B_*L_; t += GRID*4){
      const float* hp = hbuf + (size_t)t*DM + lane*8;
      f4_t v0 = *(const f4_t*)hp;
      f4_t v1 = *(const f4_t*)(hp+4);
      float ss = v0[0]*v0[0]+v0[1]*v0[1]+v0[2]*v0[2]+v0[3]*v0[3]
               + v1[0]*v1[0]+v1[1]*v1[1]+v1[2]*v1[2]+v1[3]*v1[3];
      #pragma unroll
      for (int m=32;m;m>>=1) ss += __shfl_xor(ss, m);
      float sc = rsqrtf(ss*(1.f/DM) + 1e-5f);
      const float* wp = nw + lane*8;
      f4_t w0 = *(const f4_t*)wp;
      f4_t w1 = *(const f4_t*)(wp+4);
      b8_t o;
      #pragma unroll
      for (int c=0;c<4;c++){ o[c]=(bf16_t)(v0[c]*sc*w0[c]); o[4+c]=(bf16_t)(v1[c]*sc*w1[c]); }
      *(b8_t*)(hnorm + (size_t)t*DM + lane*8) = o;
    }
    gbar(bar, barid++);

    // ===== stage 2: in_proj GEMM (M=4096,N=2048,K=512) 1024 tiles of 64x128 =====
    {
      bf16_t* As = (bf16_t*)smem;           // 64*32
      bf16_t* Ws = (bf16_t*)(smem + 4096);  // 128*32
      int wm = (wave>>1)*32, wn = (wave&1)*64;
      int lr = lane&15, q = lane>>4;
      int e0 = tid*8, r0 = e0>>5, c0 = e0&31;
      for (int item = bid; item < 1024; item += GRID){
        int m0 = (item>>4)*64, n0 = (item&15)*128;
        f4_t acc[2][4] = {};
        for (int k0=0;k0<DM;k0+=32){
          async16(hnorm + (size_t)(m0+r0)*DM + k0 + c0, As + e0);
          async16(Wi + (size_t)(n0+r0)*DM + k0 + c0,    Ws + e0);
          async16(Wi + (size_t)(n0+r0+64)*DM + k0 + c0, Ws + e0 + 2048);
          __syncthreads();
          b8_t a[2], b[4];
          #pragma unroll
          for (int i=0;i<2;i++) a[i] = *(const b8_t*)(As + (wm+i*16+lr)*32 + q*8);
          #pragma unroll
          for (int j=0;j<4;j++) b[j] = *(const b8_t*)(Ws + (wn+j*16+lr)*32 + q*8);
          #pragma unroll
          for (int i=0;i<2;i++)
            #pragma unroll
            for (int j=0;j<4;j++)
              acc[i][j] = __builtin_amdgcn_mfma_f32_16x16x32_bf16(a[i], b[j], acc[i][j], 0,0,0);
          __syncthreads();
        }
        #pragma unroll
        for (int i=0;i<2;i++)
        #pragma unroll
        for (int j=0;j<4;j++){
          int col = n0 + wn + j*16 + lr;
          int rb  = m0 + wm + i*16 + q*4;
          #pragma unroll
          for (int r=0;r<4;r++)
            xzbf[(size_t)(rb+r)*(2*DI) + col] = (bf16_t)acc[i][j][r];
        }
      }
    }
    gbar(bar, barid++);

    // ===== stage 3: conv+silu fused x_proj (split-K x4), emits xinbf; 256 tiles =====
    {
      bf16_t* As = (bf16_t*)smem;
      bf16_t* Ws = (bf16_t*)(smem + 4096);
      int wm = (wave>>1)*32, wn = (wave&1)*32;
      int lr = lane&15, q = lane>>4;
      int e0 = tid*8, r0 = e0>>5, c0 = e0&31;
      for (int item = bid; item < 256; item += GRID){
        int m0 = (item & 63)*64;
        int z = item >> 6;
        int kbase = z*256;
        int gt = m0 + r0;
        int l  = gt & (L_-1);
        f4_t acc[2][2] = {};
        for (int k0=0;k0<256;k0+=32){
          int ch = kbase + k0 + c0;
          float cv[8];
          #pragma unroll
          for (int c=0;c<8;c++) cv[c] = cb[ch+c];
          #pragma unroll
          for (int k=0;k<DC;k++){
            if (l + k - (DC-1) >= 0){
              b8_t xv = *(const b8_t*)(xzbf + (size_t)(gt + k - (DC-1))*(2*DI) + ch);
              #pragma unroll
              for (int c=0;c<8;c++) cv[c] += (float)xv[c] * cw[(ch+c)*DC + k];
            }
          }
          b8_t av;
          #pragma unroll
          for (int c=0;c<8;c++){ float s = cv[c]*sigmoidf_(cv[c]); av[c] = (bf16_t)s; }
          *(b8_t*)(As + e0) = av;
          *(b8_t*)(xinbf + (size_t)gt*DI + ch) = av;
          async16(Wxp + (size_t)r0*DI + kbase + k0 + c0, Ws + e0);
          __syncthreads();
          b8_t a[2], b[2];
          #pragma unroll
          for (int i=0;i<2;i++) a[i] = *(const b8_t*)(As + (wm+i*16+lr)*32 + q*8);
          #pragma unroll
          for (int j=0;j<2;j++) b[j] = *(const b8_t*)(Ws + (wn+j*16+lr)*32 + q*8);
          #pragma unroll
          for (int i=0;i<2;i++)
            #pragma unroll
            for (int j=0;j<2;j++)
              acc[i][j] = __builtin_amdgcn_mfma_f32_16x16x32_bf16(a[i], b[j], acc[i][j], 0,0,0);
          __syncthreads();
        }
        float* P = dbcp + (size_t)z*(B_*L_*64);
        #pragma unroll
        for (int i=0;i<2;i++)
        #pragma unroll
        for (int j=0;j<2;j++){
          int col = wn + j*16 + lr;
          int rb  = m0 + wm + i*16 + q*4;
          #pragma unroll
          for (int r=0;r<4;r++) P[(size_t)(rb+r)*64 + col] = acc[i][j][r];
        }
      }
    }
    gbar(bar, barid++);

    // ===== stage 4: partial-reduce + dt-proj + softplus -> delta bf16 (+dbc B/C); 1024 tiles =====
    {
      bf16_t* As = (bf16_t*)smem;
      bf16_t* Ws = (bf16_t*)(smem + 4096);
      const size_t S = (size_t)B_*L_*64;
      int wm = (wave>>1)*32, wn = (wave&1)*32;
      int lr = lane&15, q = lane>>4;
      int r0 = tid>>2, c0 = (tid&3)*8;
      for (int item = bid; item < 1024; item += GRID){
        int n0 = (item&15)*64, m0 = (item>>4)*64;
        int gt = m0 + r0;
        size_t base = (size_t)gt*64 + c0;
        f4_t s0 = *(const f4_t*)(dbcp + base);
        f4_t s1 = *(const f4_t*)(dbcp + base + 4);
        #pragma unroll
        for (int z=1;z<4;z++){
          s0 += *(const f4_t*)(dbcp + z*S + base);
          s1 += *(const f4_t*)(dbcp + z*S + base + 4);
        }
        b8_t av;
        #pragma unroll
        for (int c=0;c<4;c++){ av[c] = (bf16_t)s0[c]; av[4+c] = (bf16_t)s1[c]; }
        *(b8_t*)(As + tid*8) = av;
        if (n0 == 0){
          f4_t t0 = *(const f4_t*)(dbcp + base + 32);
          f4_t t1 = *(const f4_t*)(dbcp + base + 36);
          #pragma unroll
          for (int z=1;z<4;z++){
            t0 += *(const f4_t*)(dbcp + z*S + base + 32);
            t1 += *(const f4_t*)(dbcp + z*S + base + 36);
          }
          *(f4_t*)(dbc + base + 32) = t0;
          *(f4_t*)(dbc + base + 36) = t1;
        }
        async16(Wdt + (size_t)(n0+r0)*DTR + c0, Ws + tid*8);
        __syncthreads();
        b8_t a[2], b[2];
        #pragma unroll
        for (int i=0;i<2;i++) a[i] = *(const b8_t*)(As + (wm+i*16+lr)*32 + q*8);
        #pragma unroll
        for (int j=0;j<2;j++) b[j] = *(const b8_t*)(Ws + (wn+j*16+lr)*32 + q*8);
        f4_t acc[2][2] = {};
        #pragma unroll
        for (int i=0;i<2;i++)
          #pragma unroll
          for (int j=0;j<2;j++)
            acc[i][j] = __builtin_amdgcn_mfma_f32_16x16x32_bf16(a[i], b[j], acc[i][j], 0,0,0);
        #pragma unroll
        for (int i=0;i<2;i++)
        #pragma unroll
        for (int j=0;j<2;j++){
          int col = n0 + wn + j*16 + lr;
          int rb  = m0 + wm + i*16 + q*4;
          #pragma unroll
          for (int r=0;r<4;r++){
            float xv = acc[i][j][r] + dtb[col];
            float v = (xv>20.f)?xv:log1pf(__expf(xv));
            delta[(size_t)(rb+r)*DI + col] = (bf16_t)v;
          }
        }
        __syncthreads();
      }
    }
    gbar(bar, barid++);

    // ===== stage 5: scan p1 (chunk-local, h_in=0); 1024 items =====
    {
      float* Bs = (float*)smem;   // [CHUNK][DS]
      for (int item = bid; item < B_*NCHK*4; item += GRID){
        int chgrp = item & 3;
        int chunk = (item>>2) & (NCHK-1);
        int b = item >> 7;
        int ch = (chgrp<<8) + tid;
        int t0 = (b<<9) + chunk*CHUNK;
        {
          int ll = tid>>4, n = tid&15;
          Bs[ll*DS+n] = dbc[(t0+ll)*64 + DTR + n];
        }
        __syncthreads();
        float An[DS], h[DS], ap[DS];
        const f4_t* Ap = (const f4_t*)(alog + ch*DS);
        #pragma unroll
        for (int v=0;v<4;v++){
          f4_t a4 = Ap[v];
          #pragma unroll
          for (int k=0;k<4;k++){ An[v*4+k] = -__expf(a4[k]); h[v*4+k]=0.f; ap[v*4+k]=1.f; }
        }
        const bf16_t* dep = delta + (size_t)t0*DI + ch;
        const bf16_t* xp  = xinbf + (size_t)t0*DI + ch;
        #pragma unroll 8
        for (int l=0;l<CHUNK;l++){
          float de = (float)dep[(size_t)l*DI];
          float xv = (float)xp[(size_t)l*DI];
          float dx = de*xv;
          #pragma unroll
          for (int n=0;n<DS;n++){
            float dA = __expf(de*An[n]);
            h[n] = dA*h[n] + dx*Bs[l*DS+n];
            ap[n] *= dA;
          }
        }
        size_t base = ((size_t)chunk*(B_*DI) + (b<<10) + ch)*DS;
        f4_t* hp  = (f4_t*)(hend + base);
        f4_t* app = (f4_t*)(aphin + base);
        #pragma unroll
        for (int v=0;v<4;v++){
          f4_t hv, avv;
          #pragma unroll
          for (int k=0;k<4;k++){ hv[k]=h[v*4+k]; avv[k]=ap[v*4+k]; }
          hp[v]=hv; app[v]=avv;
        }
        __syncthreads();
      }
    }
    gbar(bar, barid++);

    // ===== stage 6: scan p2 (combine); 512 items =====
    for (int item = bid; item < 512; item += GRID){
      int g = item*256 + tid;
      float h = 0.f;
      for (int c=0;c<NCHK;c++){
        size_t off = (size_t)c*(B_*DI*DS) + g;
        float a = aphin[off];
        float e = hend[off];
        aphin[off] = h;
        h = a*h + e;
      }
    }
    gbar(bar, barid++);

    // ===== stage 7: scan p3 (rerun + gated y); 1024 items =====
    {
      float* Bs = (float*)smem;
      float* Cs = (float*)(smem + CHUNK*DS*4);
      for (int item = bid; item < B_*NCHK*4; item += GRID){
        int chgrp = item & 3;
        int chunk = (item>>2) & (NCHK-1);
        int b = item >> 7;
        int ch = (chgrp<<8) + tid;
        int t0 = (b<<9) + chunk*CHUNK;
        {
          int ll = tid>>4, n = tid&15;
          Bs[ll*DS+n] = dbc[(t0+ll)*64 + DTR + n];
          Cs[ll*DS+n] = dbc[(t0+ll)*64 + DTR + DS + n];
        }
        __syncthreads();
        float An[DS], h[DS];
        const f4_t* Ap = (const f4_t*)(alog + ch*DS);
        size_t base = ((size_t)chunk*(B_*DI) + (b<<10) + ch)*DS;
        const f4_t* hp = (const f4_t*)(aphin + base);
        #pragma unroll
        for (int v=0;v<4;v++){
          f4_t a4 = Ap[v];
          f4_t hv = hp[v];
          #pragma unroll
          for (int k=0;k<4;k++){ An[v*4+k] = -__expf(a4[k]); h[v*4+k]=hv[k]; }
        }
        float Dv = Dp[ch];
        const bf16_t* dep = delta + (size_t)t0*DI + ch;
        const bf16_t* zp  = xzbf + (size_t)t0*(2*DI) + DI + ch;
        const bf16_t* xp  = xinbf + (size_t)t0*DI + ch;
        bf16_t* yp = ybf + (size_t)t0*DI + ch;
        #pragma unroll 8
        for (int l=0;l<CHUNK;l++){
          float de = (float)dep[(size_t)l*DI];
          float zv = (float)zp[(size_t)l*(2*DI)];
          float xv = (float)xp[(size_t)l*DI];
          float dx = de*xv;
          float y = 0.f;
          #pragma unroll
          for (int n=0;n<DS;n++){
            float dA = __expf(de*An[n]);
            h[n] = dA*h[n] + dx*Bs[l*DS+n];
            y += h[n]*Cs[l*DS+n];
          }
          y = (y + Dv*xv) * (zv * sigmoidf_(zv));
          yp[(size_t)l*DI] = (bf16_t)y;
        }
        __syncthreads();
      }
    }
    gbar(bar, barid++);

    // ===== stage 8: out_proj GEMM h += y @ Wo^T (M=4096,N=512,K=1024); 512 tiles =====
    {
      bf16_t* As = (bf16_t*)smem;
      bf16_t* Ws = (bf16_t*)(smem + 4096);
      int wm = (wave>>1)*32, wn = (wave&1)*32;
      int lr = lane&15, q = lane>>4;
      int e0 = tid*8, r0 = e0>>5, c0 = e0&31;
      for (int item = bid; item < 512; item += GRID){
        int n0 = (item&7)*64, m0 = (item>>3)*64;
        f4_t acc[2][2] = {};
        for (int k0=0;k0<DI;k0+=32){
          async16(ybf + (size_t)(m0+r0)*DI + k0 + c0, As + e0);
          async16(Wo + (size_t)(n0+r0)*DI + k0 + c0,  Ws + e0);
          __syncthreads();
          b8_t a[2], b[2];
          #pragma unroll
          for (int i=0;i<2;i++) a[i] = *(const b8_t*)(As + (wm+i*16+lr)*32 + q*8);
          #pragma unroll
          for (int j=0;j<2;j++) b[j] = *(const b8_t*)(Ws + (wn+j*16+lr)*32 + q*8);
          #pragma unroll
          for (int i=0;i<2;i++)
            #pragma unroll
            for (int j=0;j<2;j++)
              acc[i][j] = __builtin_amdgcn_mfma_f32_16x16x32_bf16(a[i], b[j], acc[i][j], 0,0,0);
          __syncthreads();
        }
        #pragma unroll
        for (int i=0;i<2;i++)
        #pragma unroll
        for (int j=0;j<2;j++){
          int col = n0 + wn + j*16 + lr;
          int rb  = m0 + wm + i*16 + q*4;
          #pragma unroll
          for (int r=0;r<4;r++){
            size_t off = (size_t)(rb+r)*DM + col;
            hbuf[off] = hbuf[off] + acc[i][j][r];
          }
        }
      }
    }
    gbar(bar, barid++);
  }
}

// ---------- head ----------
__global__ __launch_bounds__(256) void k_head(const float* __restrict__ h, const float* __restrict__ hw,
                                              const float* __restrict__ hb, float* __restrict__ out){
  int wave = threadIdx.x>>6, lane = threadIdx.x&63;
  int gw = blockIdx.x*4 + wave;                    // < B_*HOR
  int b = gw / HOR, hh = gw % HOR;
  const float* hp = h + ((size_t)b*L_ + (L_-1))*DM;
  const float* wp = hw + (size_t)hh*DM;
  float s = 0.f;
  #pragma unroll
  for (int k=0;k<DM;k+=64) s += hp[k+lane]*wp[k+lane];
  #pragma unroll
  for (int m=32;m;m>>=1) s += __shfl_xor(s, m);
  if (lane==0) out[gw] = s + hb[hh];
}

extern "C" void kernel_launch(void* const* d_in, const int* in_sizes, int n_in,
                              void* d_out, int out_size, void* d_ws, size_t ws_size,
                              hipStream_t stream){
  const float* x    = (const float*)d_in[0];
  const float* ew   = (const float*)d_in[1];
  const float* eb   = (const float*)d_in[2];
  const float* nw   = (const float*)d_in[3];
  const float* ipw  = (const float*)d_in[4];
  const float* cw   = (const float*)d_in[5];
  const float* cb   = (const float*)d_in[6];
  const float* xpw  = (const float*)d_in[7];
  const float* dtw  = (const float*)d_in[8];
  const float* dtb  = (const float*)d_in[9];
  const float* alog = (const float*)d_in[10];
  const float* Dp   = (const float*)d_in[11];
  const float* opw  = (const float*)d_in[12];
  const float* hw   = (const float*)d_in[13];
  const float* hb   = (const float*)d_in[14];
  float* out = (float*)d_out;

  char* ws = (char*)d_ws;
  size_t o = 0;
  float*  h      = (float*)(ws + o);  o += (size_t)8<<20;    // B*L*DM f32
  bf16_t* hnorm  = (bf16_t*)(ws + o); o += (size_t)4<<20;
  bf16_t* xzbf   = (bf16_t*)(ws + o); o += (size_t)16<<20;   // B*L*2DI bf16
  bf16_t* xinbf  = (bf16_t*)(ws + o); o += (size_t)8<<20;
  bf16_t* delta  = (bf16_t*)(ws + o); o += (size_t)8<<20;    // B*L*DI bf16
  bf16_t* ybf    = (bf16_t*)(ws + o); o += (size_t)8<<20;
  float*  dbc    = (float*)(ws + o);  o += (size_t)1<<20;    // only cols 32..63 used
  float*  dbcp   = (float*)(ws + o);  o += (size_t)4<<20;    // 4 split-K partials
  bf16_t* w_in   = (bf16_t*)(ws + o); o += (size_t)8<<20;
  bf16_t* w_out  = (bf16_t*)(ws + o); o += (size_t)4<<20;
  bf16_t* w_xp   = (bf16_t*)(ws + o); o += (size_t)1<<19;
  bf16_t* w_dt   = (bf16_t*)(ws + o); o += (size_t)1<<18;
  float*  hend   = (float*)(ws + o);  o += (size_t)16<<20;   // NCHK*B*DI*DS f32
  float*  aphin  = (float*)(ws + o);  o += (size_t)16<<20;
  int*    bar    = (int*)(ws + o);    o += (size_t)32*4096;  // 32 barrier slots x 4KB

  hipMemsetAsync(bar, 0, 32*4096, stream);
  k_cvtall<<<6528,256,0,stream>>>(ipw, w_in, xpw, w_xp, dtw, w_dt, opw, w_out);
  k_embed<<<(B_*L_*DM)/256,256,0,stream>>>(x, ew, eb, h);

  k_mega<<<GRID,256,0,stream>>>(h, nw, w_in, w_xp, w_dt, w_out, cw, cb, dtb, alog, Dp,
                                hnorm, xzbf, xinbf, delta, ybf, dbc, dbcp, hend, aphin, bar);

  k_head<<<(B_*HOR)/4,256,0,stream>>>(h, hw, hb, out);
}

// Round 9
// 698.304 us; speedup vs baseline: 4.2643x; 4.2643x over previous
//
#include <hip/hip_runtime.h>
#include <hip/hip_bf16.h>

#define B_  8
#define L_  512
#define DM  512
#define NL  4
#define DS  16
#define HOR 96
#define DC  4
#define DI  1024
#define DTR 32

#define CHUNK 16
#define NCHK (L_/CHUNK)   // 32

typedef __bf16 bf16_t;
typedef __bf16 b8_t __attribute__((ext_vector_type(8)));
typedef float  f4_t __attribute__((ext_vector_type(4)));

#define LOG2E 1.44269504088896f

__device__ __forceinline__ float sigmoidf_(float x){ return 1.f/(1.f+__expf(-x)); }

__device__ __forceinline__ void async16(const bf16_t* g, bf16_t* l){
  __builtin_amdgcn_global_load_lds((const __attribute__((address_space(1))) void*)g,
                                   (__attribute__((address_space(3))) void*)l, 16, 0, 0);
}

// XOR swizzle for 32-elem (4x16B-chunk) LDS rows: logical chunk c of row r lives at c ^ ((r>>1)&3).
// Makes ds_read_b128 fragment reads 2-way (free) instead of 8-way conflicted.
__device__ __forceinline__ int swz(int row, int c){ return c ^ ((row>>1)&3); }

// ---------- fused f32 -> bf16 weight convert ----------
__global__ __launch_bounds__(256) void k_cvtall(const float* __restrict__ p0, bf16_t* __restrict__ o0,
                                                const float* __restrict__ p1, bf16_t* __restrict__ o1,
                                                const float* __restrict__ p2, bf16_t* __restrict__ o2,
                                                const float* __restrict__ p3, bf16_t* __restrict__ o3){
  int j = blockIdx.x*256 + threadIdx.x;   // v4 index
  const int S0=1048576, S1=65536, S2=32768;
  const float* src; bf16_t* dst;
  if (j < S0){ src=p0; dst=o0; }
  else if ((j-=S0) < S1){ src=p1; dst=o1; }
  else if ((j-=S1) < S2){ src=p2; dst=o2; }
  else { j-=S2; src=p3; dst=o3; }
  f4_t v = ((const f4_t*)src)[j];
  bf16_t* o = dst + (size_t)j*4;
  o[0]=(bf16_t)v[0]; o[1]=(bf16_t)v[1]; o[2]=(bf16_t)v[2]; o[3]=(bf16_t)v[3];
}

// ---------- embed ----------
__global__ __launch_bounds__(256) void k_embed(const float* __restrict__ x, const float* __restrict__ ew,
                                               const float* __restrict__ eb, float* __restrict__ h){
  int idx = blockIdx.x*256 + threadIdx.x;   // B*L*DM
  int d = idx & (DM-1); int t = idx >> 9;
  h[idx] = x[t]*ew[d] + eb[d];
}

// ---------- rmsnorm (fp32 in, bf16 out) ----------
__global__ __launch_bounds__(256) void k_rms(const float* __restrict__ h, const float* __restrict__ w,
                                             bf16_t* __restrict__ o){
  int t = blockIdx.x; int tid = threadIdx.x;
  const float* hp = h + (size_t)t*DM;
  float v0 = hp[tid], v1 = hp[tid+256];
  float s = v0*v0 + v1*v1;
  #pragma unroll
  for (int m=32;m;m>>=1) s += __shfl_xor(s, m);
  __shared__ float red[4];
  if ((tid&63)==0) red[tid>>6]=s;
  __syncthreads();
  float tot = red[0]+red[1]+red[2]+red[3];
  float sc = rsqrtf(tot*(1.f/DM) + 1e-5f);
  o[(size_t)t*DM + tid]       = (bf16_t)(v0*sc*w[tid]);
  o[(size_t)t*DM + tid + 256] = (bf16_t)(v1*sc*w[tid+256]);
}

// ---------- TM=64 swizzled bf16 MFMA GEMM: C[M,N] = A[M,K] @ W[N,K]^T ----------
// MODE 0: bf16 out | 3: resid+acc f32
template<int TN, int MODE>
__global__ __launch_bounds__(256) void k_g64(const bf16_t* __restrict__ A, int lda,
                                             const bf16_t* __restrict__ W, int ldw,
                                             float* __restrict__ C, int ldc, int K,
                                             bf16_t* __restrict__ Cbf){
  constexpr int NJ = TN/32;
  __shared__ bf16_t As[64*32];
  __shared__ bf16_t Ws[TN*32];
  int tid = threadIdx.x;
  int m0 = blockIdx.y*64, n0 = blockIdx.x*TN;
  int wave = tid>>6, lane = tid&63;
  int wm = (wave>>1)*32, wn = (wave&1)*(TN/2);
  int lr = lane&15, q = lane>>4;
  int r0 = tid>>2;
  int gco = swz(r0, tid&3)*8;                 // swizzled source column
  int aoff[2], boff[NJ];
  #pragma unroll
  for (int i=0;i<2;i++){ int rw = wm+i*16+lr; aoff[i] = rw*32 + swz(rw,q)*8; }
  #pragma unroll
  for (int j=0;j<NJ;j++){ int rw = wn+j*16+lr; boff[j] = rw*32 + swz(rw,q)*8; }
  f4_t acc[2][NJ] = {};
  for (int k0=0;k0<K;k0+=32){
    async16(A + (size_t)(m0+r0)*lda + k0 + gco, As + tid*8);
    async16(W + (size_t)(n0+r0)*ldw + k0 + gco, Ws + tid*8);
    if (TN==128)
      async16(W + (size_t)(n0+r0+64)*ldw + k0 + gco, Ws + tid*8 + 2048);
    __syncthreads();
    b8_t a[2], b[NJ];
    #pragma unroll
    for (int i=0;i<2;i++) a[i] = *(const b8_t*)(As + aoff[i]);
    #pragma unroll
    for (int j=0;j<NJ;j++) b[j] = *(const b8_t*)(Ws + boff[j]);
    #pragma unroll
    for (int i=0;i<2;i++)
      #pragma unroll
      for (int j=0;j<NJ;j++)
        acc[i][j] = __builtin_amdgcn_mfma_f32_16x16x32_bf16(a[i], b[j], acc[i][j], 0,0,0);
    __syncthreads();
  }
  #pragma unroll
  for (int i=0;i<2;i++)
  #pragma unroll
  for (int j=0;j<NJ;j++){
    int col = n0 + wn + j*16 + lr;
    int rb  = m0 + wm + i*16 + q*4;
    #pragma unroll
    for (int r=0;r<4;r++){
      size_t off = (size_t)(rb+r)*ldc + col;
      float v = acc[i][j][r];
      if (MODE==0){ Cbf[off] = (bf16_t)v; }
      else { C[off] = C[off] + v; }
    }
  }
}

// ---------- x_proj GEMM with conv+silu fused into A staging (split-K x4); emits xinbf; swizzled ----------
__global__ __launch_bounds__(256) void k_dbc(const bf16_t* __restrict__ xzbf, const float* __restrict__ cw,
                                             const float* __restrict__ cb, const bf16_t* __restrict__ wxp,
                                             float* __restrict__ part, bf16_t* __restrict__ xinbf){
  __shared__ bf16_t As[64*32];
  __shared__ bf16_t Ws[64*32];
  int tid = threadIdx.x;
  int m0 = blockIdx.x*64;
  int z = blockIdx.y;
  int kbase = z*256;
  int wave = tid>>6, lane = tid&63;
  int wm = (wave>>1)*32, wn = (wave&1)*32;
  int lr = lane&15, q = lane>>4;
  int r0 = tid>>2;
  int gco = swz(r0, tid&3)*8;
  int aoff[2], boff[2];
  #pragma unroll
  for (int i=0;i<2;i++){ int rw = wm+i*16+lr; aoff[i] = rw*32 + swz(rw,q)*8; }
  #pragma unroll
  for (int j=0;j<2;j++){ int rw = wn+j*16+lr; boff[j] = rw*32 + swz(rw,q)*8; }
  int gt = m0 + r0;              // global token
  int l  = gt & (L_-1);          // position within batch
  f4_t acc[2][2] = {};
  for (int k0=0;k0<256;k0+=32){
    int ch = kbase + k0 + gco;   // 8 channels ch..ch+7 (swizzled slot)
    float cv[8];
    #pragma unroll
    for (int c=0;c<8;c++) cv[c] = cb[ch+c];
    #pragma unroll
    for (int k=0;k<DC;k++){
      if (l + k - (DC-1) >= 0){
        b8_t xv = *(const b8_t*)(xzbf + (size_t)(gt + k - (DC-1))*(2*DI) + ch);
        #pragma unroll
        for (int c=0;c<8;c++) cv[c] += (float)xv[c] * cw[(ch+c)*DC + k];
      }
    }
    b8_t av;
    #pragma unroll
    for (int c=0;c<8;c++){ float s = cv[c]*sigmoidf_(cv[c]); av[c] = (bf16_t)s; }
    *(b8_t*)(As + tid*8) = av;
    *(b8_t*)(xinbf + (size_t)gt*DI + ch) = av;     // each (token,channel) written once
    async16(wxp + (size_t)r0*DI + kbase + k0 + gco, Ws + tid*8);
    __syncthreads();
    b8_t a[2], b[2];
    #pragma unroll
    for (int i=0;i<2;i++) a[i] = *(const b8_t*)(As + aoff[i]);
    #pragma unroll
    for (int j=0;j<2;j++) b[j] = *(const b8_t*)(Ws + boff[j]);
    #pragma unroll
    for (int i=0;i<2;i++)
      #pragma unroll
      for (int j=0;j<2;j++)
        acc[i][j] = __builtin_amdgcn_mfma_f32_16x16x32_bf16(a[i], b[j], acc[i][j], 0,0,0);
    __syncthreads();
  }
  float* P = part + (size_t)z*(B_*L_*64);
  #pragma unroll
  for (int i=0;i<2;i++)
  #pragma unroll
  for (int j=0;j<2;j++){
    int col = wn + j*16 + lr;
    int rb  = m0 + wm + i*16 + q*4;
    #pragma unroll
    for (int r=0;r<4;r++) P[(size_t)(rb+r)*64 + col] = acc[i][j][r];
  }
}

// ---------- fused: partial-reduce + dt-proj + softplus -> delta bf16; n-block0 writes dbc B/C f32 ----------
__global__ __launch_bounds__(256) void k_dt(const float* __restrict__ part, const bf16_t* __restrict__ wdt,
                                            const float* __restrict__ dtb, float* __restrict__ dbc,
                                            bf16_t* __restrict__ delta){
  __shared__ bf16_t As[64*32];
  __shared__ bf16_t Ws[64*32];
  int tid = threadIdx.x;
  int m0 = blockIdx.y*64, n0 = blockIdx.x*64;
  const size_t S = (size_t)B_*L_*64;
  int r0 = tid>>2, c0 = (tid&3)*8;
  int gco = swz(r0, tid&3)*8;
  int gt = m0 + r0;
  size_t base0 = (size_t)gt*64;
  f4_t s0 = *(const f4_t*)(part + base0 + gco);
  f4_t s1 = *(const f4_t*)(part + base0 + gco + 4);
  #pragma unroll
  for (int z=1;z<4;z++){
    s0 += *(const f4_t*)(part + z*S + base0 + gco);
    s1 += *(const f4_t*)(part + z*S + base0 + gco + 4);
  }
  b8_t av;
  #pragma unroll
  for (int c=0;c<4;c++){ av[c] = (bf16_t)s0[c]; av[4+c] = (bf16_t)s1[c]; }
  *(b8_t*)(As + tid*8) = av;
  if (n0 == 0){   // reduce + store B/C columns (32..64) in f32
    f4_t t0 = *(const f4_t*)(part + base0 + c0 + 32);
    f4_t t1 = *(const f4_t*)(part + base0 + c0 + 36);
    #pragma unroll
    for (int z=1;z<4;z++){
      t0 += *(const f4_t*)(part + z*S + base0 + c0 + 32);
      t1 += *(const f4_t*)(part + z*S + base0 + c0 + 36);
    }
    *(f4_t*)(dbc + base0 + c0 + 32) = t0;
    *(f4_t*)(dbc + base0 + c0 + 36) = t1;
  }
  async16(wdt + (size_t)(n0+r0)*DTR + gco, Ws + tid*8);
  __syncthreads();
  int wave = tid>>6, lane = tid&63;
  int wm = (wave>>1)*32, wn = (wave&1)*32;
  int lr = lane&15, q = lane>>4;
  b8_t a[2], b[2];
  #pragma unroll
  for (int i=0;i<2;i++){ int rw = wm+i*16+lr; a[i] = *(const b8_t*)(As + rw*32 + swz(rw,q)*8); }
  #pragma unroll
  for (int j=0;j<2;j++){ int rw = wn+j*16+lr; b[j] = *(const b8_t*)(Ws + rw*32 + swz(rw,q)*8); }
  f4_t acc[2][2] = {};
  #pragma unroll
  for (int i=0;i<2;i++)
    #pragma unroll
    for (int j=0;j<2;j++)
      acc[i][j] = __builtin_amdgcn_mfma_f32_16x16x32_bf16(a[i], b[j], acc[i][j], 0,0,0);
  #pragma unroll
  for (int i=0;i<2;i++)
  #pragma unroll
  for (int j=0;j<2;j++){
    int col = n0 + wn + j*16 + lr;
    int rb  = m0 + wm + i*16 + q*4;
    #pragma unroll
    for (int r=0;r<4;r++){
      float xv = acc[i][j][r] + dtb[col];
      float v = (xv>20.f)?xv:log1pf(__expf(xv));
      delta[(size_t)(rb+r)*DI + col] = (bf16_t)v;
    }
  }
}

// ---------- scan phase 1: per-chunk local scan (h_in=0); exp2 + ap=exp2(An2*sum(de)); bf16 out ----------
__global__ __launch_bounds__(256) void k_scan_p1(const bf16_t* __restrict__ delta, const bf16_t* __restrict__ xin,
                                                 const float* __restrict__ dbc, const float* __restrict__ Alog,
                                                 bf16_t* __restrict__ hend, bf16_t* __restrict__ aprod){
  int tid = threadIdx.x;
  int blk = blockIdx.x;
  int chgrp = blk & 3;
  int chunk = (blk>>2) & (NCHK-1);
  int b = blk >> 7;
  int ch = (chgrp<<8) + tid;
  int t0 = (b<<9) + chunk*CHUNK;
  __shared__ float Bs[CHUNK][DS];
  {
    int ll = tid>>4, n = tid&15;
    Bs[ll][n] = dbc[(t0+ll)*64 + DTR + n];
  }
  __syncthreads();
  float An2[DS], h[DS];
  const f4_t* Ap = (const f4_t*)(Alog + ch*DS);
  #pragma unroll
  for (int v=0;v<4;v++){
    f4_t a4 = Ap[v];
    #pragma unroll
    for (int k=0;k<4;k++){ An2[v*4+k] = -__expf(a4[k])*LOG2E; h[v*4+k]=0.f; }
  }
  float sde = 0.f;
  const bf16_t* dep = delta + (size_t)t0*DI + ch;
  const bf16_t* xp  = xin   + (size_t)t0*DI + ch;
  #pragma unroll 8
  for (int l=0;l<CHUNK;l++){
    float de = (float)dep[(size_t)l*DI];
    float xv = (float)xp[(size_t)l*DI];
    float dx = de*xv;
    sde += de;
    #pragma unroll
    for (int n=0;n<DS;n++){
      float dA = exp2f(de*An2[n]);
      h[n] = dA*h[n] + dx*Bs[l][n];
    }
  }
  size_t base = ((size_t)chunk*(B_*DI) + (b<<10) + ch)*DS;
  b8_t hv[2], av[2];
  #pragma unroll
  for (int v=0;v<2;v++)
    #pragma unroll
    for (int k=0;k<8;k++){
      hv[v][k] = (bf16_t)h[v*8+k];
      av[v][k] = (bf16_t)exp2f(An2[v*8+k]*sde);
    }
  ((b8_t*)(hend + base))[0] = hv[0]; ((b8_t*)(hend + base))[1] = hv[1];
  ((b8_t*)(aprod + base))[0] = av[0]; ((b8_t*)(aprod + base))[1] = av[1];
}

// ---------- scan phase 2: combine chunk transitions (bf16 in, bf16 hin out into aprod) ----------
__global__ __launch_bounds__(256) void k_scan_p2(const bf16_t* __restrict__ hend, bf16_t* __restrict__ ap_hin){
  int g = blockIdx.x*256 + threadIdx.x;   // B_*DI*DS
  float h = 0.f;
  for (int c=0;c<NCHK;c++){
    size_t off = (size_t)c*(B_*DI*DS) + g;
    float a = (float)ap_hin[off];
    float e = (float)hend[off];
    ap_hin[off] = (bf16_t)h;
    h = a*h + e;
  }
}

// ---------- scan phase 3: rerun with h_in, produce gated y (bf16) ----------
__global__ __launch_bounds__(256) void k_scan_p3(const bf16_t* __restrict__ delta, const bf16_t* __restrict__ xz,
                                                 const bf16_t* __restrict__ xin,
                                                 const float* __restrict__ dbc, const float* __restrict__ Alog,
                                                 const bf16_t* __restrict__ hin, const float* __restrict__ Dp,
                                                 bf16_t* __restrict__ ybf){
  int tid = threadIdx.x;
  int blk = blockIdx.x;
  int chgrp = blk & 3;
  int chunk = (blk>>2) & (NCHK-1);
  int b = blk >> 7;
  int ch = (chgrp<<8) + tid;
  int t0 = (b<<9) + chunk*CHUNK;
  __shared__ float Bs[CHUNK][DS];
  __shared__ float Cs[CHUNK][DS];
  {
    int ll = tid>>4, n = tid&15;
    Bs[ll][n] = dbc[(t0+ll)*64 + DTR + n];
    Cs[ll][n] = dbc[(t0+ll)*64 + DTR + DS + n];
  }
  __syncthreads();
  float An2[DS], h[DS];
  const f4_t* Ap = (const f4_t*)(Alog + ch*DS);
  size_t base = ((size_t)chunk*(B_*DI) + (b<<10) + ch)*DS;
  b8_t h0 = ((const b8_t*)(hin + base))[0];
  b8_t h1 = ((const b8_t*)(hin + base))[1];
  #pragma unroll
  for (int v=0;v<4;v++){
    f4_t a4 = Ap[v];
    #pragma unroll
    for (int k=0;k<4;k++){
      An2[v*4+k] = -__expf(a4[k])*LOG2E;
      int idx = v*4+k;
      h[idx] = (idx<8) ? (float)h0[idx] : (float)h1[idx-8];
    }
  }
  float Dv = Dp[ch];
  const bf16_t* dep = delta + (size_t)t0*DI + ch;
  const bf16_t* zp  = xz + (size_t)t0*(2*DI) + DI + ch;
  const bf16_t* xp  = xin + (size_t)t0*DI + ch;
  bf16_t* yp = ybf + (size_t)t0*DI + ch;
  #pragma unroll 8
  for (int l=0;l<CHUNK;l++){
    float de = (float)dep[(size_t)l*DI];
    float zv = (float)zp[(size_t)l*(2*DI)];
    float xv = (float)xp[(size_t)l*DI];
    float dx = de*xv;
    float y = 0.f;
    #pragma unroll
    for (int n=0;n<DS;n++){
      float dA = exp2f(de*An2[n]);
      h[n] = dA*h[n] + dx*Bs[l][n];
      y += h[n]*Cs[l][n];
    }
    y = (y + Dv*xv) * (zv * sigmoidf_(zv));
    yp[(size_t)l*DI] = (bf16_t)y;
  }
}

// ---------- head ----------
__global__ __launch_bounds__(256) void k_head(const float* __restrict__ h, const float* __restrict__ hw,
                                              const float* __restrict__ hb, float* __restrict__ out){
  int wave = threadIdx.x>>6, lane = threadIdx.x&63;
  int gw = blockIdx.x*4 + wave;                    // < B_*HOR
  int b = gw / HOR, hh = gw % HOR;
  const float* hp = h + ((size_t)b*L_ + (L_-1))*DM;
  const float* wp = hw + (size_t)hh*DM;
  float s = 0.f;
  #pragma unroll
  for (int k=0;k<DM;k+=64) s += hp[k+lane]*wp[k+lane];
  #pragma unroll
  for (int m=32;m;m>>=1) s += __shfl_xor(s, m);
  if (lane==0) out[gw] = s + hb[hh];
}

extern "C" void kernel_launch(void* const* d_in, const int* in_sizes, int n_in,
                              void* d_out, int out_size, void* d_ws, size_t ws_size,
                              hipStream_t stream){
  const float* x    = (const float*)d_in[0];
  const float* ew   = (const float*)d_in[1];
  const float* eb   = (const float*)d_in[2];
  const float* nw   = (const float*)d_in[3];
  const float* ipw  = (const float*)d_in[4];
  const float* cw   = (const float*)d_in[5];
  const float* cb   = (const float*)d_in[6];
  const float* xpw  = (const float*)d_in[7];
  const float* dtw  = (const float*)d_in[8];
  const float* dtb  = (const float*)d_in[9];
  const float* alog = (const float*)d_in[10];
  const float* Dp   = (const float*)d_in[11];
  const float* opw  = (const float*)d_in[12];
  const float* hw   = (const float*)d_in[13];
  const float* hb   = (const float*)d_in[14];
  float* out = (float*)d_out;

  char* ws = (char*)d_ws;
  size_t o = 0;
  float*  h      = (float*)(ws + o);  o += (size_t)8<<20;    // B*L*DM f32
  bf16_t* hnorm  = (bf16_t*)(ws + o); o += (size_t)4<<20;
  bf16_t* xzbf   = (bf16_t*)(ws + o); o += (size_t)16<<20;   // B*L*2DI bf16
  bf16_t* xinbf  = (bf16_t*)(ws + o); o += (size_t)8<<20;
  bf16_t* delta  = (bf16_t*)(ws + o); o += (size_t)8<<20;    // B*L*DI bf16
  bf16_t* ybf    = (bf16_t*)(ws + o); o += (size_t)8<<20;
  float*  dbc    = (float*)(ws + o);  o += (size_t)1<<20;    // only cols 32..63 used
  float*  dbcp   = (float*)(ws + o);  o += (size_t)4<<20;    // 4 split-K partials
  bf16_t* w_in   = (bf16_t*)(ws + o); o += (size_t)8<<20;
  bf16_t* w_out  = (bf16_t*)(ws + o); o += (size_t)4<<20;
  bf16_t* w_xp   = (bf16_t*)(ws + o); o += (size_t)1<<19;
  bf16_t* w_dt   = (bf16_t*)(ws + o); o += (size_t)1<<18;
  bf16_t* hend   = (bf16_t*)(ws + o); o += (size_t)8<<20;    // NCHK*B*DI*DS bf16
  bf16_t* aphin  = (bf16_t*)(ws + o); o += (size_t)8<<20;    // ~86 MB total

  k_cvtall<<<6528,256,0,stream>>>(ipw, w_in, xpw, w_xp, dtw, w_dt, opw, w_out);
  k_embed<<<(B_*L_*DM)/256,256,0,stream>>>(x, ew, eb, h);

  for (int i=0;i<NL;i++){
    k_rms<<<B_*L_,256,0,stream>>>(h, nw + i*DM, hnorm);
    // xz(bf16) = hnorm @ in_proj^T   (M=4096,N=2048,K=512) -- 1024 blocks
    k_g64<128,0><<<dim3(2*DI/128, B_*L_/64),256,0,stream>>>(
        hnorm, DM, w_in + (size_t)i*2*DI*DM, DM, nullptr, 2*DI, DM, xzbf);
    // dbc partials = silu(conv(xz)) @ x_proj^T  (split-K x4, conv fused, xinbf emitted)
    k_dbc<<<dim3(B_*L_/64, 4),256,0,stream>>>(xzbf, cw + i*DI*DC, cb + i*DI,
                                              w_xp + (size_t)i*64*DI, dbcp, xinbf);
    // delta(bf16) = softplus(sum(partials)[:, :32] @ dt_w^T + dt_b); dbc B/C by n-block 0
    k_dt<<<dim3(DI/64, B_*L_/64),256,0,stream>>>(dbcp, w_dt + (size_t)i*DI*DTR,
                                                 dtb + i*DI, dbc, delta);
    // chunked selective scan (3-phase, CHUNK=16, bf16 state round-trips)
    k_scan_p1<<<B_*NCHK*4,256,0,stream>>>(delta, xinbf, dbc, alog + i*DI*DS, hend, aphin);
    k_scan_p2<<<(B_*DI*DS)/256,256,0,stream>>>(hend, aphin);
    k_scan_p3<<<B_*NCHK*4,256,0,stream>>>(delta, xzbf, xinbf, dbc, alog + i*DI*DS,
                                          aphin, Dp + i*DI, ybf);
    // h = h + y @ out_proj^T   (M=4096,N=512,K=1024) -- 512 blocks
    k_g64<64,3><<<dim3(DM/64, B_*L_/64),256,0,stream>>>(
        ybf, DI, w_out + (size_t)i*DM*DI, DI, h, DM, DI, nullptr);
  }
  k_head<<<(B_*HOR)/4,256,0,stream>>>(h, hw, hb, out);
}

// Round 10
// 641.137 us; speedup vs baseline: 4.6445x; 1.0892x over previous
//
#include <hip/hip_runtime.h>
#include <hip/hip_bf16.h>

#define B_  8
#define L_  512
#define DM  512
#define NL  4
#define DS  16
#define HOR 96
#define DC  4
#define DI  1024
#define DTR 32

#define CHUNK 16
#define NCHK (L_/CHUNK)   // 32

typedef __bf16 bf16_t;
typedef __bf16 b8_t __attribute__((ext_vector_type(8)));
typedef float  f4_t __attribute__((ext_vector_type(4)));

#define LOG2E 1.44269504088896f

__device__ __forceinline__ float sigmoidf_(float x){ return 1.f/(1.f+__expf(-x)); }

__device__ __forceinline__ void async16(const bf16_t* g, bf16_t* l){
  __builtin_amdgcn_global_load_lds((const __attribute__((address_space(1))) void*)g,
                                   (__attribute__((address_space(3))) void*)l, 16, 0, 0);
}

// ---------- fused f32 -> bf16 weight convert ----------
__global__ __launch_bounds__(256) void k_cvtall(const float* __restrict__ p0, bf16_t* __restrict__ o0,
                                                const float* __restrict__ p1, bf16_t* __restrict__ o1,
                                                const float* __restrict__ p2, bf16_t* __restrict__ o2,
                                                const float* __restrict__ p3, bf16_t* __restrict__ o3){
  int j = blockIdx.x*256 + threadIdx.x;   // v4 index
  const int S0=1048576, S1=65536, S2=32768;
  const float* src; bf16_t* dst;
  if (j < S0){ src=p0; dst=o0; }
  else if ((j-=S0) < S1){ src=p1; dst=o1; }
  else if ((j-=S1) < S2){ src=p2; dst=o2; }
  else { j-=S2; src=p3; dst=o3; }
  f4_t v = ((const f4_t*)src)[j];
  bf16_t* o = dst + (size_t)j*4;
  o[0]=(bf16_t)v[0]; o[1]=(bf16_t)v[1]; o[2]=(bf16_t)v[2]; o[3]=(bf16_t)v[3];
}

// ---------- embed ----------
__global__ __launch_bounds__(256) void k_embed(const float* __restrict__ x, const float* __restrict__ ew,
                                               const float* __restrict__ eb, float* __restrict__ h){
  int idx = blockIdx.x*256 + threadIdx.x;   // B*L*DM
  int d = idx & (DM-1); int t = idx >> 9;
  h[idx] = x[t]*ew[d] + eb[d];
}

// ---------- rmsnorm (fp32 in, bf16 out) ----------
__global__ __launch_bounds__(256) void k_rms(const float* __restrict__ h, const float* __restrict__ w,
                                             bf16_t* __restrict__ o){
  int t = blockIdx.x; int tid = threadIdx.x;
  const float* hp = h + (size_t)t*DM;
  float v0 = hp[tid], v1 = hp[tid+256];
  float s = v0*v0 + v1*v1;
  #pragma unroll
  for (int m=32;m;m>>=1) s += __shfl_xor(s, m);
  __shared__ float red[4];
  if ((tid&63)==0) red[tid>>6]=s;
  __syncthreads();
  float tot = red[0]+red[1]+red[2]+red[3];
  float sc = rsqrtf(tot*(1.f/DM) + 1e-5f);
  o[(size_t)t*DM + tid]       = (bf16_t)(v0*sc*w[tid]);
  o[(size_t)t*DM + tid + 256] = (bf16_t)(v1*sc*w[tid+256]);
}

// ---------- TM=64 bf16 MFMA GEMM: C[M,N] = A[M,K] @ W[N,K]^T ----------
// MODE 0: bf16 out | 3: resid+acc f32
template<int TN, int MODE>
__global__ __launch_bounds__(256) void k_g64(const bf16_t* __restrict__ A, int lda,
                                             const bf16_t* __restrict__ W, int ldw,
                                             float* __restrict__ C, int ldc, int K,
                                             bf16_t* __restrict__ Cbf){
  constexpr int NJ = TN/32;
  __shared__ bf16_t As[64*32];
  __shared__ bf16_t Ws[TN*32];
  int tid = threadIdx.x;
  int m0 = blockIdx.y*64, n0 = blockIdx.x*TN;
  int wave = tid>>6, lane = tid&63;
  int wm = (wave>>1)*32, wn = (wave&1)*(TN/2);
  int lr = lane&15, q = lane>>4;
  int e0 = tid*8, r0 = e0>>5, c0 = e0&31;
  f4_t acc[2][NJ] = {};
  for (int k0=0;k0<K;k0+=32){
    async16(A + (size_t)(m0+r0)*lda + k0 + c0, As + e0);
    async16(W + (size_t)(n0+r0)*ldw + k0 + c0, Ws + e0);
    if (TN==128)
      async16(W + (size_t)(n0+r0+64)*ldw + k0 + c0, Ws + e0 + 2048);
    __syncthreads();
    b8_t a[2], b[NJ];
    #pragma unroll
    for (int i=0;i<2;i++) a[i] = *(const b8_t*)(As + (wm+i*16+lr)*32 + q*8);
    #pragma unroll
    for (int j=0;j<NJ;j++) b[j] = *(const b8_t*)(Ws + (wn+j*16+lr)*32 + q*8);
    #pragma unroll
    for (int i=0;i<2;i++)
      #pragma unroll
      for (int j=0;j<NJ;j++)
        acc[i][j] = __builtin_amdgcn_mfma_f32_16x16x32_bf16(a[i], b[j], acc[i][j], 0,0,0);
    __syncthreads();
  }
  #pragma unroll
  for (int i=0;i<2;i++)
  #pragma unroll
  for (int j=0;j<NJ;j++){
    int col = n0 + wn + j*16 + lr;
    int rb  = m0 + wm + i*16 + q*4;
    #pragma unroll
    for (int r=0;r<4;r++){
      size_t off = (size_t)(rb+r)*ldc + col;
      float v = acc[i][j][r];
      if (MODE==0){ Cbf[off] = (bf16_t)v; }
      else { C[off] = C[off] + v; }
    }
  }
}

// ---------- x_proj GEMM with conv+silu fused into A staging (split-K x4); also emits xinbf ----------
__global__ __launch_bounds__(256) void k_dbc(const bf16_t* __restrict__ xzbf, const float* __restrict__ cw,
                                             const float* __restrict__ cb, const bf16_t* __restrict__ wxp,
                                             float* __restrict__ part, bf16_t* __restrict__ xinbf){
  __shared__ bf16_t As[64*32];
  __shared__ bf16_t Ws[64*32];
  int tid = threadIdx.x;
  int m0 = blockIdx.x*64;
  int z = blockIdx.y;
  int kbase = z*256;
  int wave = tid>>6, lane = tid&63;
  int wm = (wave>>1)*32, wn = (wave&1)*32;
  int lr = lane&15, q = lane>>4;
  int e0 = tid*8, r0 = e0>>5, c0 = e0&31;
  int gt = m0 + r0;              // global token
  int l  = gt & (L_-1);          // position within batch
  f4_t acc[2][2] = {};
  for (int k0=0;k0<256;k0+=32){
    int ch = kbase + k0 + c0;    // 8 channels ch..ch+7
    float cv[8];
    #pragma unroll
    for (int c=0;c<8;c++) cv[c] = cb[ch+c];
    #pragma unroll
    for (int k=0;k<DC;k++){
      if (l + k - (DC-1) >= 0){
        b8_t xv = *(const b8_t*)(xzbf + (size_t)(gt + k - (DC-1))*(2*DI) + ch);
        #pragma unroll
        for (int c=0;c<8;c++) cv[c] += (float)xv[c] * cw[(ch+c)*DC + k];
      }
    }
    b8_t av;
    #pragma unroll
    for (int c=0;c<8;c++){ float s = cv[c]*sigmoidf_(cv[c]); av[c] = (bf16_t)s; }
    *(b8_t*)(As + e0) = av;
    *(b8_t*)(xinbf + (size_t)gt*DI + ch) = av;     // each (token,channel) written once
    async16(wxp + (size_t)r0*DI + kbase + k0 + c0, Ws + e0);
    __syncthreads();
    b8_t a[2], b[2];
    #pragma unroll
    for (int i=0;i<2;i++) a[i] = *(const b8_t*)(As + (wm+i*16+lr)*32 + q*8);
    #pragma unroll
    for (int j=0;j<2;j++) b[j] = *(const b8_t*)(Ws + (wn+j*16+lr)*32 + q*8);
    #pragma unroll
    for (int i=0;i<2;i++)
      #pragma unroll
      for (int j=0;j<2;j++)
        acc[i][j] = __builtin_amdgcn_mfma_f32_16x16x32_bf16(a[i], b[j], acc[i][j], 0,0,0);
    __syncthreads();
  }
  float* P = part + (size_t)z*(B_*L_*64);
  #pragma unroll
  for (int i=0;i<2;i++)
  #pragma unroll
  for (int j=0;j<2;j++){
    int col = wn + j*16 + lr;
    int rb  = m0 + wm + i*16 + q*4;
    #pragma unroll
    for (int r=0;r<4;r++) P[(size_t)(rb+r)*64 + col] = acc[i][j][r];
  }
}

// ---------- fused: partial-reduce + dt-proj + softplus -> delta bf16; n-block0 writes dbc B/C f32 ----------
__global__ __launch_bounds__(256) void k_dt(const float* __restrict__ part, const bf16_t* __restrict__ wdt,
                                            const float* __restrict__ dtb, float* __restrict__ dbc,
                                            bf16_t* __restrict__ delta){
  __shared__ bf16_t As[64*32];
  __shared__ bf16_t Ws[64*32];
  int tid = threadIdx.x;
  int m0 = blockIdx.y*64, n0 = blockIdx.x*64;
  const size_t S = (size_t)B_*L_*64;
  int r0 = tid>>2, c0 = (tid&3)*8;
  int gt = m0 + r0;
  size_t base = (size_t)gt*64 + c0;
  f4_t s0 = *(const f4_t*)(part + base);
  f4_t s1 = *(const f4_t*)(part + base + 4);
  #pragma unroll
  for (int z=1;z<4;z++){
    s0 += *(const f4_t*)(part + z*S + base);
    s1 += *(const f4_t*)(part + z*S + base + 4);
  }
  b8_t av;
  #pragma unroll
  for (int c=0;c<4;c++){ av[c] = (bf16_t)s0[c]; av[4+c] = (bf16_t)s1[c]; }
  *(b8_t*)(As + tid*8) = av;
  if (n0 == 0){   // reduce + store B/C columns (32..64) in f32
    f4_t t0 = *(const f4_t*)(part + base + 32);
    f4_t t1 = *(const f4_t*)(part + base + 36);
    #pragma unroll
    for (int z=1;z<4;z++){
      t0 += *(const f4_t*)(part + z*S + base + 32);
      t1 += *(const f4_t*)(part + z*S + base + 36);
    }
    *(f4_t*)(dbc + base + 32) = t0;
    *(f4_t*)(dbc + base + 36) = t1;
  }
  async16(wdt + (size_t)(n0+r0)*DTR + c0, Ws + tid*8);
  __syncthreads();
  int wave = tid>>6, lane = tid&63;
  int wm = (wave>>1)*32, wn = (wave&1)*32;
  int lr = lane&15, q = lane>>4;
  b8_t a[2], b[2];
  #pragma unroll
  for (int i=0;i<2;i++) a[i] = *(const b8_t*)(As + (wm+i*16+lr)*32 + q*8);
  #pragma unroll
  for (int j=0;j<2;j++) b[j] = *(const b8_t*)(Ws + (wn+j*16+lr)*32 + q*8);
  f4_t acc[2][2] = {};
  #pragma unroll
  for (int i=0;i<2;i++)
    #pragma unroll
    for (int j=0;j<2;j++)
      acc[i][j] = __builtin_amdgcn_mfma_f32_16x16x32_bf16(a[i], b[j], acc[i][j], 0,0,0);
  #pragma unroll
  for (int i=0;i<2;i++)
  #pragma unroll
  for (int j=0;j<2;j++){
    int col = n0 + wn + j*16 + lr;
    int rb  = m0 + wm + i*16 + q*4;
    #pragma unroll
    for (int r=0;r<4;r++){
      float xv = acc[i][j][r] + dtb[col];
      float v = (xv>20.f)?xv:log1pf(__expf(xv));
      delta[(size_t)(rb+r)*DI + col] = (bf16_t)v;
    }
  }
}

// ---------- scan phase 1: LDS-staged chunk-local scan (h_in=0); bf16 state out ----------
__global__ __launch_bounds__(256) void k_scan_p1(const bf16_t* __restrict__ delta, const bf16_t* __restrict__ xin,
                                                 const float* __restrict__ dbc, const float* __restrict__ Alog,
                                                 bf16_t* __restrict__ hend, bf16_t* __restrict__ aprod){
  __shared__ bf16_t des[CHUNK][256];
  __shared__ bf16_t xs[CHUNK][256];
  __shared__ float Bs[CHUNK][DS];
  int tid = threadIdx.x;
  int blk = blockIdx.x;
  int chgrp = blk & 3;
  int chunk = (blk>>2) & (NCHK-1);
  int b = blk >> 7;
  int ch0 = chgrp<<8;
  int ch = ch0 + tid;
  int t0 = (b<<9) + chunk*CHUNK;
  // stage de, x tiles (coalesced 16B loads) + B
  #pragma unroll
  for (int idx=tid; idx<CHUNK*32; idx+=256){
    int row = idx>>5, c = (idx&31)*8;
    *(b8_t*)(&des[row][c]) = *(const b8_t*)(delta + (size_t)(t0+row)*DI + ch0 + c);
    *(b8_t*)(&xs[row][c])  = *(const b8_t*)(xin   + (size_t)(t0+row)*DI + ch0 + c);
  }
  {
    int ll = tid>>4, n = tid&15;
    Bs[ll][n] = dbc[(t0+ll)*64 + DTR + n];
  }
  __syncthreads();
  float An2[DS], h[DS];
  const f4_t* Ap = (const f4_t*)(Alog + ch*DS);
  #pragma unroll
  for (int v=0;v<4;v++){
    f4_t a4 = Ap[v];
    #pragma unroll
    for (int k=0;k<4;k++){ An2[v*4+k] = -__expf(a4[k])*LOG2E; h[v*4+k]=0.f; }
  }
  float sde = 0.f;
  #pragma unroll
  for (int l=0;l<CHUNK;l++){
    float de = (float)des[l][tid];
    float xv = (float)xs[l][tid];
    float dx = de*xv;
    sde += de;
    #pragma unroll
    for (int n=0;n<DS;n++){
      float dA = exp2f(de*An2[n]);
      h[n] = dA*h[n] + dx*Bs[l][n];
    }
  }
  size_t base = ((size_t)chunk*(B_*DI) + (b<<10) + ch)*DS;
  b8_t hv[2], av[2];
  #pragma unroll
  for (int v=0;v<2;v++)
    #pragma unroll
    for (int k=0;k<8;k++){
      hv[v][k] = (bf16_t)h[v*8+k];
      av[v][k] = (bf16_t)exp2f(An2[v*8+k]*sde);
    }
  ((b8_t*)(hend + base))[0] = hv[0]; ((b8_t*)(hend + base))[1] = hv[1];
  ((b8_t*)(aprod + base))[0] = av[0]; ((b8_t*)(aprod + base))[1] = av[1];
}

// ---------- scan phase 2: combine chunk transitions (bf16 in, bf16 hin out into aprod) ----------
__global__ __launch_bounds__(256) void k_scan_p2(const bf16_t* __restrict__ hend, bf16_t* __restrict__ ap_hin){
  int g = blockIdx.x*256 + threadIdx.x;   // B_*DI*DS
  float h = 0.f;
  for (int c=0;c<NCHK;c++){
    size_t off = (size_t)c*(B_*DI*DS) + g;
    float a = (float)ap_hin[off];
    float e = (float)hend[off];
    ap_hin[off] = (bf16_t)h;
    h = a*h + e;
  }
}

// ---------- scan phase 3: LDS-staged rerun with h_in, produce gated y (bf16) ----------
__global__ __launch_bounds__(256) void k_scan_p3(const bf16_t* __restrict__ delta, const bf16_t* __restrict__ xz,
                                                 const bf16_t* __restrict__ xin,
                                                 const float* __restrict__ dbc, const float* __restrict__ Alog,
                                                 const bf16_t* __restrict__ hin, const float* __restrict__ Dp,
                                                 bf16_t* __restrict__ ybf){
  __shared__ bf16_t des[CHUNK][256];
  __shared__ bf16_t xs[CHUNK][256];
  __shared__ bf16_t zs[CHUNK][256];
  __shared__ float Bs[CHUNK][DS];
  __shared__ float Cs[CHUNK][DS];
  int tid = threadIdx.x;
  int blk = blockIdx.x;
  int chgrp = blk & 3;
  int chunk = (blk>>2) & (NCHK-1);
  int b = blk >> 7;
  int ch0 = chgrp<<8;
  int ch = ch0 + tid;
  int t0 = (b<<9) + chunk*CHUNK;
  #pragma unroll
  for (int idx=tid; idx<CHUNK*32; idx+=256){
    int row = idx>>5, c = (idx&31)*8;
    *(b8_t*)(&des[row][c]) = *(const b8_t*)(delta + (size_t)(t0+row)*DI + ch0 + c);
    *(b8_t*)(&xs[row][c])  = *(const b8_t*)(xin   + (size_t)(t0+row)*DI + ch0 + c);
    *(b8_t*)(&zs[row][c])  = *(const b8_t*)(xz + (size_t)(t0+row)*(2*DI) + DI + ch0 + c);
  }
  {
    int ll = tid>>4, n = tid&15;
    Bs[ll][n] = dbc[(t0+ll)*64 + DTR + n];
    Cs[ll][n] = dbc[(t0+ll)*64 + DTR + DS + n];
  }
  __syncthreads();
  float An2[DS], h[DS];
  const f4_t* Ap = (const f4_t*)(Alog + ch*DS);
  size_t base = ((size_t)chunk*(B_*DI) + (b<<10) + ch)*DS;
  b8_t h0 = ((const b8_t*)(hin + base))[0];
  b8_t h1 = ((const b8_t*)(hin + base))[1];
  #pragma unroll
  for (int v=0;v<4;v++){
    f4_t a4 = Ap[v];
    #pragma unroll
    for (int k=0;k<4;k++){
      An2[v*4+k] = -__expf(a4[k])*LOG2E;
      int idx = v*4+k;
      h[idx] = (idx<8) ? (float)h0[idx] : (float)h1[idx-8];
    }
  }
  float Dv = Dp[ch];
  bf16_t* yp = ybf + (size_t)t0*DI + ch;
  #pragma unroll
  for (int l=0;l<CHUNK;l++){
    float de = (float)des[l][tid];
    float zv = (float)zs[l][tid];
    float xv = (float)xs[l][tid];
    float dx = de*xv;
    float y = 0.f;
    #pragma unroll
    for (int n=0;n<DS;n++){
      float dA = exp2f(de*An2[n]);
      h[n] = dA*h[n] + dx*Bs[l][n];
      y += h[n]*Cs[l][n];
    }
    y = (y + Dv*xv) * (zv * sigmoidf_(zv));
    yp[(size_t)l*DI] = (bf16_t)y;
  }
}

// ---------- head ----------
__global__ __launch_bounds__(256) void k_head(const float* __restrict__ h, const float* __restrict__ hw,
                                              const float* __restrict__ hb, float* __restrict__ out){
  int wave = threadIdx.x>>6, lane = threadIdx.x&63;
  int gw = blockIdx.x*4 + wave;                    // < B_*HOR
  int b = gw / HOR, hh = gw % HOR;
  const float* hp = h + ((size_t)b*L_ + (L_-1))*DM;
  const float* wp = hw + (size_t)hh*DM;
  float s = 0.f;
  #pragma unroll
  for (int k=0;k<DM;k+=64) s += hp[k+lane]*wp[k+lane];
  #pragma unroll
  for (int m=32;m;m>>=1) s += __shfl_xor(s, m);
  if (lane==0) out[gw] = s + hb[hh];
}

extern "C" void kernel_launch(void* const* d_in, const int* in_sizes, int n_in,
                              void* d_out, int out_size, void* d_ws, size_t ws_size,
                              hipStream_t stream){
  const float* x    = (const float*)d_in[0];
  const float* ew   = (const float*)d_in[1];
  const float* eb   = (const float*)d_in[2];
  const float* nw   = (const float*)d_in[3];
  const float* ipw  = (const float*)d_in[4];
  const float* cw   = (const float*)d_in[5];
  const float* cb   = (const float*)d_in[6];
  const float* xpw  = (const float*)d_in[7];
  const float* dtw  = (const float*)d_in[8];
  const float* dtb  = (const float*)d_in[9];
  const float* alog = (const float*)d_in[10];
  const float* Dp   = (const float*)d_in[11];
  const float* opw  = (const float*)d_in[12];
  const float* hw   = (const float*)d_in[13];
  const float* hb   = (const float*)d_in[14];
  float* out = (float*)d_out;

  char* ws = (char*)d_ws;
  size_t o = 0;
  float*  h      = (float*)(ws + o);  o += (size_t)8<<20;    // B*L*DM f32
  bf16_t* hnorm  = (bf16_t*)(ws + o); o += (size_t)4<<20;
  bf16_t* xzbf   = (bf16_t*)(ws + o); o += (size_t)16<<20;   // B*L*2DI bf16
  bf16_t* xinbf  = (bf16_t*)(ws + o); o += (size_t)8<<20;
  bf16_t* delta  = (bf16_t*)(ws + o); o += (size_t)8<<20;    // B*L*DI bf16
  bf16_t* ybf    = (bf16_t*)(ws + o); o += (size_t)8<<20;
  float*  dbc    = (float*)(ws + o);  o += (size_t)1<<20;    // only cols 32..63 used
  float*  dbcp   = (float*)(ws + o);  o += (size_t)4<<20;    // 4 split-K partials
  bf16_t* w_in   = (bf16_t*)(ws + o); o += (size_t)8<<20;
  bf16_t* w_out  = (bf16_t*)(ws + o); o += (size_t)4<<20;
  bf16_t* w_xp   = (bf16_t*)(ws + o); o += (size_t)1<<19;
  bf16_t* w_dt   = (bf16_t*)(ws + o); o += (size_t)1<<18;
  bf16_t* hend   = (bf16_t*)(ws + o); o += (size_t)8<<20;    // NCHK*B*DI*DS bf16
  bf16_t* aphin  = (bf16_t*)(ws + o); o += (size_t)8<<20;    // ~86 MB total

  k_cvtall<<<6528,256,0,stream>>>(ipw, w_in, xpw, w_xp, dtw, w_dt, opw, w_out);
  k_embed<<<(B_*L_*DM)/256,256,0,stream>>>(x, ew, eb, h);

  for (int i=0;i<NL;i++){
    k_rms<<<B_*L_,256,0,stream>>>(h, nw + i*DM, hnorm);
    // xz(bf16) = hnorm @ in_proj^T   (M=4096,N=2048,K=512) -- 1024 blocks
    k_g64<128,0><<<dim3(2*DI/128, B_*L_/64),256,0,stream>>>(
        hnorm, DM, w_in + (size_t)i*2*DI*DM, DM, nullptr, 2*DI, DM, xzbf);
    // dbc partials = silu(conv(xz)) @ x_proj^T  (split-K x4, conv fused, xinbf emitted)
    k_dbc<<<dim3(B_*L_/64, 4),256,0,stream>>>(xzbf, cw + i*DI*DC, cb + i*DI,
                                              w_xp + (size_t)i*64*DI, dbcp, xinbf);
    // delta(bf16) = softplus(sum(partials)[:, :32] @ dt_w^T + dt_b); dbc B/C by n-block 0
    k_dt<<<dim3(DI/64, B_*L_/64),256,0,stream>>>(dbcp, w_dt + (size_t)i*DI*DTR,
                                                 dtb + i*DI, dbc, delta);
    // chunked selective scan (3-phase, LDS-staged, CHUNK=16)
    k_scan_p1<<<B_*NCHK*4,256,0,stream>>>(delta, xinbf, dbc, alog + i*DI*DS, hend, aphin);
    k_scan_p2<<<(B_*DI*DS)/256,256,0,stream>>>(hend, aphin);
    k_scan_p3<<<B_*NCHK*4,256,0,stream>>>(delta, xzbf, xinbf, dbc, alog + i*DI*DS,
                                          aphin, Dp + i*DI, ybf);
    // h = h + y @ out_proj^T   (M=4096,N=512,K=1024) -- 512 blocks
    k_g64<64,3><<<dim3(DM/64, B_*L_/64),256,0,stream>>>(
        ybf, DI, w_out + (size_t)i*DM*DI, DI, h, DM, DI, nullptr);
  }
  k_head<<<(B_*HOR)/4,256,0,stream>>>(h, hw, hb, out);
}